// Round 16
// baseline (94.264 us; speedup 1.0000x reference)
//
#include <hip/hip_runtime.h>
#include <hip/hip_fp16.h>
#include <math.h>

#define NQ    14
#define DIM   16384
#define DEPTH 4

typedef __attribute__((ext_vector_type(2))) float f2;
typedef __attribute__((ext_vector_type(4))) float f4;
typedef __half2 h2;

__device__ __forceinline__ f2 cmul(f2 a, f2 b) {
    return (f2){a.x*b.x - a.y*b.y, a.x*b.y + a.y*b.x};
}
__device__ __forceinline__ float czsgn(int e) {
    return (__popc(e & (e >> 1)) & 1) ? -1.0f : 1.0f;
}

// ---------------- fp16-plane state (r15, HW-verified) ----------------
// r16: + wave de-phasing. Within a half-layer the 7 gates act on DISTINCT
// qubits -> exact commutation -> per-wave gate order is free. Waves of
// alternating parity p=(w^(w>>2))&1 (alternates within a SIMD under either
// wave->SIMD mapping) run the sequence forward vs reversed, so the 4 waves
// sharing a SIMD hit coefficient-load waits / chain tails at different
// program points instead of in lockstep (r15 falsified the issue-bound
// model: halving VALU work moved the wall only ~2.5us).

// complex butterfly on planes: (or,oi) = c1*x + c2*y
__device__ __forceinline__ void cfma2(h2 c1r, h2 c1i, h2 c2r, h2 c2i,
                                      h2 xr, h2 xi, h2 yr, h2 yi,
                                      h2& or_, h2& oi_)
{
    or_ = __hfma2(c1r, xr, __hfma2(__hneg2(c1i), xi,
          __hfma2(c2r, yr, __hmul2(__hneg2(c2i), yi))));
    oi_ = __hfma2(c1r, xi, __hfma2(c1i, xr,
          __hfma2(c2r, yi, __hmul2(c2i, yr))));
}

__device__ __forceinline__ h2 hxor(h2 v, unsigned m) {
    union { h2 h; unsigned u; } x; x.h = v; x.u ^= m; return x.h;
}

template<int CTRL>
__device__ __forceinline__ h2 dpph(h2 v) {
    union { h2 h; int i; } u, r;
    u.h = v;
    r.i = __builtin_amdgcn_update_dpp(0, u.i, CTRL, 0xF, 0xF, true);
    return r.h;
}
template<int XB> __device__ __forceinline__ h2 lx2(h2 v);
template<> __device__ __forceinline__ h2 lx2<1>(h2 v) { return dpph<0xB1>(v); }   // quad_perm [1,0,3,2]
template<> __device__ __forceinline__ h2 lx2<2>(h2 v) { return dpph<0x4E>(v); }   // quad_perm [2,3,0,1]
template<> __device__ __forceinline__ h2 lx2<8>(h2 v) { return dpph<0x128>(v); }  // row_ror:8 == xor8

// reg gate, cross-pair (pair-index mask KM in {4,2,1} <-> l-mask {8,4,2})
template<int KM>
__device__ __forceinline__ void reg_gate_h(h2 hr[8], h2 hi[8], const h2* __restrict__ g) {
    h2 c00r = g[0], c00i = g[1], c01r = g[2], c01i = g[3];
    h2 c10r = g[4], c10i = g[5], c11r = g[6], c11i = g[7];
    #pragma unroll
    for (int k = 0; k < 8; ++k) {
        if (k & KM) continue;
        const int j = k | KM;
        h2 xr = hr[k], xi = hi[k], yr = hr[j], yi = hi[j];
        cfma2(c00r, c00i, c01r, c01i, xr, xi, yr, yi, hr[k], hi[k]);
        cfma2(c10r, c10i, c11r, c11i, xr, xi, yr, yi, hr[j], hi[j]);
    }
}

// within-pair gate (l-mask 1): partner = swapped halves; coeffs column-packed
// A=(u00,u11), B=(u01,u10)
__device__ __forceinline__ void pair_gate_h(h2 hr[8], h2 hi[8], const h2* __restrict__ g) {
    h2 Ar = g[0], Ai = g[1], Br = g[2], Bi = g[3];
    #pragma unroll
    for (int k = 0; k < 8; ++k) {
        h2 pr = __lowhigh2highlow(hr[k]);
        h2 pi = __lowhigh2highlow(hi[k]);
        cfma2(Ar, Ai, Br, Bi, hr[k], hi[k], pr, pi, hr[k], hi[k]);
    }
}

// lane gate: DPP partner; per-lane row select (lo: u00,u01; hi: u11,u10)
template<int XB>
__device__ __forceinline__ void lane_gate_h(h2 hr[8], h2 hi[8], const h2* __restrict__ g, int t) {
    const bool hiL = (t & XB) != 0;
    h2 c1r = hiL ? g[6] : g[0];
    h2 c1i = hiL ? g[7] : g[1];
    h2 c2r = hiL ? g[4] : g[2];
    h2 c2i = hiL ? g[5] : g[3];
    #pragma unroll
    for (int k = 0; k < 8; ++k) {
        h2 pr = lx2<XB>(hr[k]);
        h2 pi = lx2<XB>(hi[k]);
        cfma2(c1r, c1i, c2r, c2i, hr[k], hi[k], pr, pi, hr[k], hi[k]);
    }
}

// CZ signs as sign-bit XOR. View A: e=(l<<10)|(n<<4)|w (verified r10).
__device__ __forceinline__ void cz_A_h(h2 hr[8], h2 hi[8], int t) {
    const int n = t & 63, w = t >> 6;
    const int pT = (__popc(w & (w >> 1)) + __popc(n & (n >> 1)) + ((n & 1) & (w >> 3))) & 1;
    const int f0 = pT, f1 = pT ^ ((n >> 5) & 1);   // F1: cross term l0 & n5
    #pragma unroll
    for (int k = 0; k < 8; ++k) {
        const int stlo = __popc((2*k) & ((2*k) >> 1)) & 1;
        const int sthi = __popc((2*k+1) & ((2*k+1) >> 1)) & 1;
        const unsigned mask = ((f0 ^ stlo) ? 0x8000u : 0u)
                            | ((f1 ^ sthi) ? 0x80000000u : 0u);
        hr[k] = hxor(hr[k], mask); hi[k] = hxor(hi[k], mask);
    }
}
// View B: e9=n3,e8=n1,e7=n5,e6=n0,e5=n4,e4=n2 (verified r10); cross = l3&n2.
__device__ __forceinline__ void cz_B_h(h2 hr[8], h2 hi[8], int t) {
    const int n = t & 63, w = t >> 6;
    const int n0 = n & 1, n1 = (n >> 1) & 1, n2 = (n >> 2) & 1;
    const int n3 = (n >> 3) & 1, n4 = (n >> 4) & 1, n5 = (n >> 5) & 1;
    const int pT = ((n2 & n4) ^ (n4 & n0) ^ (n0 & n5) ^ (n5 & n1) ^ (n1 & n3)
                    ^ (n3 & (w & 1)) ^ (__popc(w & (w >> 1)) & 1));
    const int f0 = pT, f1 = pT ^ n2;
    #pragma unroll
    for (int k = 0; k < 8; ++k) {
        const int fs = (k & 4) ? f1 : f0;           // l3 = k&4 selects F
        const int stlo = __popc((2*k) & ((2*k) >> 1)) & 1;
        const int sthi = __popc((2*k+1) & ((2*k+1) >> 1)) & 1;
        const unsigned mask = ((fs ^ stlo) ? 0x8000u : 0u)
                            | ((fs ^ sthi) ? 0x80000000u : 0u);
        hr[k] = hxor(hr[k], mask); hi[k] = hxor(hi[k], mask);
    }
}

// half-layer gate bodies, forward and reversed (gates commute: distinct qubits)
__device__ __forceinline__ void half_fwd(h2 hr[8], h2 hi[8],
                                         const h2* __restrict__ g, int t) {
    reg_gate_h<4>(hr, hi, g + 0*8);
    reg_gate_h<2>(hr, hi, g + 1*8);
    reg_gate_h<1>(hr, hi, g + 2*8);
    pair_gate_h(hr, hi, g + 3*8);
    lane_gate_h<8>(hr, hi, g + 4*8, t);
    lane_gate_h<2>(hr, hi, g + 5*8, t);
    lane_gate_h<1>(hr, hi, g + 6*8, t);
}
__device__ __forceinline__ void half_rev(h2 hr[8], h2 hi[8],
                                         const h2* __restrict__ g, int t) {
    lane_gate_h<1>(hr, hi, g + 6*8, t);
    lane_gate_h<2>(hr, hi, g + 5*8, t);
    lane_gate_h<8>(hr, hi, g + 4*8, t);
    pair_gate_h(hr, hi, g + 3*8);
    reg_gate_h<1>(hr, hi, g + 2*8);
    reg_gate_h<2>(hr, hi, g + 1*8);
    reg_gate_h<4>(hr, hi, g + 0*8);
}

// ---- prep: gates -> d_ws (batch-invariant; 1 block) ----
__global__ void qlg_prep(const float* __restrict__ wts, h2* __restrict__ Gh,
                         f4* __restrict__ G0)
{
    const int t = threadIdx.x;
    if (t >= DEPTH * NQ) return;
    const int d = t / NQ, ww = t % NQ;
    const float p0 = wts[(d*NQ + ww)*3 + 0];
    const float p1 = wts[(d*NQ + ww)*3 + 1];
    const float p2 = wts[(d*NQ + ww)*3 + 2];
    float s0, c0, s1, c1, s2, c2;
    sincosf(0.5f*p0, &s0, &c0);
    sincosf(0.5f*p1, &s1, &c1);
    sincosf(0.5f*p2, &s2, &c2);
    // U = RY(p2) * RX(p1) * RZ(p0)
    f2 e0  = (f2){c0, -s0};
    f2 e0c = (f2){c0,  s0};
    f2 is1 = (f2){0.f, -s1};
    f2 m00 = c1 * e0;
    f2 m01 = cmul(is1, e0c);
    f2 m10 = cmul(is1, e0);
    f2 m11 = c1 * e0c;
    f2 u00 = c2*m00 - s2*m10;
    f2 u01 = c2*m01 - s2*m11;
    f2 u10 = s2*m00 + c2*m10;
    f2 u11 = s2*m01 + c2*m11;
    if (d == 0) {
        G0[ww*2 + 0] = (f4){u00.x, u00.y, u01.x, u01.y};
        G0[ww*2 + 1] = (f4){u10.x, u10.y, u11.x, u11.y};
        return;
    }
    // half-layers h0..h5 = (1,A),(1,B),(2,B),(2,A),(3,A),(3,B);
    // slots: A: q0,q1,q2,q3,q6,q8,q9   B: q10,q11,q12,q13,q4,q5,q7
    const bool isA = (ww <= 3) || (ww == 6) || (ww == 8) || (ww == 9);
    int slot;
    if (isA) slot = (ww <= 3) ? ww : (ww == 6 ? 4 : (ww == 8 ? 5 : 6));
    else     slot = (ww >= 10) ? (ww - 10) : (ww == 4 ? 4 : (ww == 5 ? 5 : 6));
    const int h = (d == 1) ? (isA ? 0 : 1)
                : (d == 2) ? (isA ? 3 : 2)
                           : (isA ? 4 : 5);
    h2* g = Gh + (h*7 + slot)*8;
    if (slot == 3) {   // within-pair gate: column packing A=(u00,u11) B=(u01,u10)
        g[0] = __halves2half2(__float2half_rn(u00.x), __float2half_rn(u11.x));
        g[1] = __halves2half2(__float2half_rn(u00.y), __float2half_rn(u11.y));
        g[2] = __halves2half2(__float2half_rn(u01.x), __float2half_rn(u10.x));
        g[3] = __halves2half2(__float2half_rn(u01.y), __float2half_rn(u10.y));
        g[4] = g[5] = g[6] = g[7] = __float2half2_rn(0.f);
    } else {           // broadcast packing
        g[0] = __float2half2_rn(u00.x); g[1] = __float2half2_rn(u00.y);
        g[2] = __float2half2_rn(u01.x); g[3] = __float2half2_rn(u01.y);
        g[4] = __float2half2_rn(u10.x); g[5] = __float2half2_rn(u10.y);
        g[6] = __float2half2_rn(u11.x); g[7] = __float2half2_rn(u11.y);
    }
}

__global__ __launch_bounds__(1024)
void qlg_kernel(const float* __restrict__ cond,
                const float* __restrict__ Wenc,
                const float* __restrict__ benc,
                const h2* __restrict__ Gh,
                const f4* __restrict__ G0,
                float* __restrict__ out)
{
    __shared__ h2 st[DIM];                  // 64 KB remap buffer (f16 amps)
    __shared__ f2 qv[NQ][2];
    __shared__ f2 Phi[128];
    __shared__ f2 Plo[128];
    __shared__ float embS[NQ];
    __shared__ float wred[16][NQ];
    __shared__ float lat[NQ];

    const int b = blockIdx.x;
    const int t = threadIdx.x;
    const int n = t & 63, w = t >> 6;
    const int bB = (w << 10)
                 | (((n >> 3) & 1) << 5) | (((n >> 1) & 1) << 4)
                 | (((n >> 5) & 1) << 3) | ((n & 1) << 2)
                 | (((n >> 4) & 1) << 1) | ((n >> 2) & 1);
    const int pdx = (w ^ (w >> 2)) & 1;     // de-phase parity (alternates on a SIMD)

    // ---- stage 1: embedding (SiLU) ----
    if (t < NQ) {
        float s = benc[t];
        #pragma unroll
        for (int k = 0; k < NQ; ++k) s += cond[b*NQ + k] * Wenc[t*NQ + k];
        embS[t] = s / (1.0f + __expf(-s));
    }
    __syncthreads();

    // ---- stage 2: per-wire 2-vectors after encoding + layer 0 (fp32) ----
    if (t < NQ) {
        float v = embS[t];
        float s, c;
        sincosf(0.5f*v, &s, &c);
        f2 a0 = (f2){c*c,  s*s};
        f2 a1 = (f2){s*c, -s*c};
        f4 va = G0[t*2], vb = G0[t*2 + 1];
        f2 u00 = (f2){va.x, va.y}, u01 = (f2){va.z, va.w};
        f2 u10 = (f2){vb.x, vb.y}, u11 = (f2){vb.z, vb.w};
        qv[t][0] = cmul(u00, a0) + cmul(u01, a1);
        qv[t][1] = cmul(u10, a0) + cmul(u11, a1);
    }
    __syncthreads();

    // ---- stage 3: partial-product tables (fp32) ----
    if (t < 128) {
        f2 p = qv[0][(t >> 6) & 1];
        #pragma unroll
        for (int ww = 1; ww <= 6; ++ww) p = cmul(p, qv[ww][(t >> (6 - ww)) & 1]);
        Phi[t] = p;
    } else if (t < 256) {
        const int j = t - 128;
        f2 p = qv[7][(j >> 6) & 1];
        #pragma unroll
        for (int ww = 8; ww <= 13; ++ww) p = cmul(p, qv[ww][(j >> (13 - ww)) & 1]);
        Plo[j] = p;
    }
    __syncthreads();

    // ---- stage 4: build product state in f16 planes (view A), CZ0 fused ----
    h2 hr[8], hi[8];
    {
        f2 plo = Plo[((n & 7) << 4) | w];
        #pragma unroll
        for (int k = 0; k < 8; ++k) {
            const int l0 = 2*k, l1 = 2*k + 1;
            const int e0 = (l0 << 10) | (n << 4) | w;
            const int e1 = (l1 << 10) | (n << 4) | w;
            f2 a0 = cmul(Phi[(l0 << 3) | (n >> 3)], plo) * czsgn(e0);
            f2 a1 = cmul(Phi[(l1 << 3) | (n >> 3)], plo) * czsgn(e1);
            hr[k] = __floats2half2_rn(a0.x, a1.x);
            hi[k] = __floats2half2_rn(a0.y, a1.y);
        }
    }

    // ---- stage 5: 6 half-layers; alternating waves run reversed gate order ----
    #pragma unroll
    for (int h = 0; h < 6; ++h) {
        const h2* __restrict__ g = Gh + h*7*8;
        if (pdx == 0) half_fwd(hr, hi, g, t);
        else          half_rev(hr, hi, g, t);
        if (h == 1)      cz_B_h(hr, hi, t); // CZ after layer 1 (view B)
        else if (h == 3) cz_A_h(hr, hi, t); // CZ after layer 2 (view A)
        if (h == 0 || h == 4) {             // remap A -> B
            #pragma unroll
            for (int k = 0; k < 8; ++k) {
                st[t + ((2*k)   << 10)] = __halves2half2(__low2half(hr[k]),  __low2half(hi[k]));
                st[t + ((2*k+1) << 10)] = __halves2half2(__high2half(hr[k]), __high2half(hi[k]));
            }
            __syncthreads();
            #pragma unroll
            for (int k = 0; k < 8; ++k) {
                h2 w0 = st[bB + ((2*k)   << 6)];
                h2 w1 = st[bB + ((2*k+1) << 6)];
                hr[k] = __halves2half2(__low2half(w0),  __low2half(w1));
                hi[k] = __halves2half2(__high2half(w0), __high2half(w1));
            }
        } else if (h == 2) {                // remap B -> A
            #pragma unroll
            for (int k = 0; k < 8; ++k) {
                st[bB + ((2*k)   << 6)] = __halves2half2(__low2half(hr[k]),  __low2half(hi[k]));
                st[bB + ((2*k+1) << 6)] = __halves2half2(__high2half(hr[k]), __high2half(hi[k]));
            }
            __syncthreads();
            #pragma unroll
            for (int k = 0; k < 8; ++k) {
                h2 w0 = st[t + ((2*k)   << 10)];
                h2 w1 = st[t + ((2*k+1) << 10)];
                hr[k] = __halves2half2(__low2half(w0),  __low2half(w1));
                hi[k] = __halves2half2(__high2half(w0), __high2half(w1));
            }
        }
    }
    // (CZ after layer 3 dropped: |psi|^2 invariant)

    // ---- fused probability reduction (view B, fp32 accumulate) ----
    float SU, Q10, Q11, Q12, Q13;
    {
        SU = Q10 = Q11 = Q12 = Q13 = 0.f;
        #pragma unroll
        for (int k = 0; k < 8; ++k) {
            float2 fr = __half22float2(hr[k]);
            float2 fi = __half22float2(hi[k]);
            float pl = fr.x*fr.x + fi.x*fi.x;
            float ph = fr.y*fr.y + fi.y*fi.y;
            float g2 = pl + ph;
            SU  += g2;
            Q13 += pl - ph;                 // l0
            Q10 += (k & 4) ? -g2 : g2;      // l3
            Q11 += (k & 2) ? -g2 : g2;      // l2
            Q12 += (k & 1) ? -g2 : g2;      // l1
        }
    }

    // ---- stage 6: reduce to 14 expectations, layernorm (fp32) ----
    // View-B thread-uniform sign bits: q0:t9 q1:t8 q2:t7 q3:t6 q4:t3 q5:t1
    // q6:t5 q7:t0 q8:t4 q9:t2.
    {
        const int lane = t & 63, wv = t >> 6;
        const int sbit[10] = {9, 8, 7, 6, 3, 1, 5, 0, 4, 2};
        #pragma unroll
        for (int ww = 0; ww < NQ; ++ww) {
            float v;
            if      (ww == 10) v = Q10;
            else if (ww == 11) v = Q11;
            else if (ww == 12) v = Q12;
            else if (ww == 13) v = Q13;
            else               v = ((t >> sbit[ww]) & 1) ? -SU : SU;
            #pragma unroll
            for (int off = 32; off > 0; off >>= 1) v += __shfl_down(v, off, 64);
            if (lane == 0) wred[wv][ww] = v;
        }
    }
    __syncthreads();
    if (t < NQ) {
        float s = 0.f;
        #pragma unroll
        for (int k = 0; k < 16; ++k) s += wred[k][t];
        lat[t] = s;
    }
    __syncthreads();
    if (t < NQ) {
        float mu = 0.f;
        #pragma unroll
        for (int k = 0; k < NQ; ++k) mu += lat[k];
        mu *= (1.0f / NQ);
        float var = 0.f;
        #pragma unroll
        for (int k = 0; k < NQ; ++k) { float dv = lat[k] - mu; var += dv*dv; }
        var *= (1.0f / NQ);
        out[b*NQ + t] = (lat[t] - mu) * rsqrtf(var + 1e-5f);
    }
}

extern "C" void kernel_launch(void* const* d_in, const int* in_sizes, int n_in,
                              void* d_out, int out_size, void* d_ws, size_t ws_size,
                              hipStream_t stream)
{
    (void)n_in; (void)ws_size; (void)out_size;
    const float* cond = (const float*)d_in[0];
    const float* Wenc = (const float*)d_in[1];
    const float* benc = (const float*)d_in[2];
    const float* wts  = (const float*)d_in[3];
    float* out = (float*)d_out;
    h2* Gh = (h2*)d_ws;                          // 336 h2 = 1344 B
    f4* G0 = (f4*)((char*)d_ws + 2048);          // 28 f4 = 448 B
    const int B = in_sizes[0] / NQ;              // 256
    qlg_prep<<<dim3(1), dim3(64), 0, stream>>>(wts, Gh, G0);
    qlg_kernel<<<dim3(B), dim3(1024), 0, stream>>>(cond, Wenc, benc, Gh, G0, out);
}

// Round 17
// 92.262 us; speedup vs baseline: 1.0217x; 1.0217x over previous
//
#include <hip/hip_runtime.h>
#include <math.h>

#define NQ    14
#define DIM   16384
#define DEPTH 4

typedef __attribute__((ext_vector_type(2))) float f2;
typedef __attribute__((ext_vector_type(4))) float f4;
typedef __attribute__((ext_vector_type(2))) _Float16 hf2;   // -> v_pk_*_f16

__device__ __forceinline__ f2 cmul(f2 a, f2 b) {
    return (f2){a.x*b.x - a.y*b.y, a.x*b.y + a.y*b.x};
}
__device__ __forceinline__ float czsgn(int e) {
    return (__popc(e & (e >> 1)) & 1) ? -1.0f : 1.0f;
}
__device__ __forceinline__ hf2 h2of(float a, float b) {
    return (hf2){(_Float16)a, (_Float16)b};
}

// ---------------- fp16-plane state (r15 structure, HW-verified) ----------
// r17: all plane math as NATIVE ext_vector _Float16 expressions. Theory:
// __hfma2/__hneg2 intrinsics lowered poorly (r15's halved instruction count
// moved the wall only ~3us while fp32 VALU-busy had matched the pk_f32 cycle
// model exactly across r5-r14) — native vector ops are the reliably-lowered
// path to v_pk_fma_f16 with neg modifiers folded.

// complex butterfly on planes: (or,oi) = c1*x + c2*y  (1 pk_mul + 3 pk_fma x2)
__device__ __forceinline__ void cfma2(hf2 c1r, hf2 c1i, hf2 c2r, hf2 c2i,
                                      hf2 xr, hf2 xi, hf2 yr, hf2 yi,
                                      hf2& or_, hf2& oi_)
{
    or_ = c1r*xr - c1i*xi + c2r*yr - c2i*yi;
    oi_ = c1r*xi + c1i*xr + c2r*yi + c2i*yr;
}

__device__ __forceinline__ hf2 hxor(hf2 v, unsigned m) {
    union { hf2 h; unsigned u; } x; x.h = v; x.u ^= m; return x.h;
}
__device__ __forceinline__ hf2 hswap(hf2 v) {
    return __builtin_shufflevector(v, v, 1, 0);
}

template<int CTRL>
__device__ __forceinline__ hf2 dpph(hf2 v) {
    union { hf2 h; int i; } u, r;
    u.h = v;
    r.i = __builtin_amdgcn_update_dpp(0, u.i, CTRL, 0xF, 0xF, true);
    return r.h;
}
template<int XB> __device__ __forceinline__ hf2 lx2(hf2 v);
template<> __device__ __forceinline__ hf2 lx2<1>(hf2 v) { return dpph<0xB1>(v); }   // quad_perm [1,0,3,2]
template<> __device__ __forceinline__ hf2 lx2<2>(hf2 v) { return dpph<0x4E>(v); }   // quad_perm [2,3,0,1]
template<> __device__ __forceinline__ hf2 lx2<8>(hf2 v) { return dpph<0x128>(v); }  // row_ror:8 == xor8

// reg gate, cross-pair (pair-index mask KM in {4,2,1} <-> l-mask {8,4,2})
template<int KM>
__device__ __forceinline__ void reg_gate_h(hf2 hr[8], hf2 hi[8], const hf2* __restrict__ g) {
    hf2 c00r = g[0], c00i = g[1], c01r = g[2], c01i = g[3];
    hf2 c10r = g[4], c10i = g[5], c11r = g[6], c11i = g[7];
    #pragma unroll
    for (int k = 0; k < 8; ++k) {
        if (k & KM) continue;
        const int j = k | KM;
        hf2 xr = hr[k], xi = hi[k], yr = hr[j], yi = hi[j];
        cfma2(c00r, c00i, c01r, c01i, xr, xi, yr, yi, hr[k], hi[k]);
        cfma2(c10r, c10i, c11r, c11i, xr, xi, yr, yi, hr[j], hi[j]);
    }
}

// within-pair gate (l-mask 1): partner = swapped halves; coeffs column-packed
// A=(u00,u11), B=(u01,u10)
__device__ __forceinline__ void pair_gate_h(hf2 hr[8], hf2 hi[8], const hf2* __restrict__ g) {
    hf2 Ar = g[0], Ai = g[1], Br = g[2], Bi = g[3];
    #pragma unroll
    for (int k = 0; k < 8; ++k) {
        hf2 pr = hswap(hr[k]);
        hf2 pi = hswap(hi[k]);
        cfma2(Ar, Ai, Br, Bi, hr[k], hi[k], pr, pi, hr[k], hi[k]);
    }
}

// lane gate: DPP partner; per-lane row select (lo: u00,u01; hi: u11,u10)
template<int XB>
__device__ __forceinline__ void lane_gate_h(hf2 hr[8], hf2 hi[8], const hf2* __restrict__ g, int t) {
    const bool hiL = (t & XB) != 0;
    hf2 c1r = hiL ? g[6] : g[0];
    hf2 c1i = hiL ? g[7] : g[1];
    hf2 c2r = hiL ? g[4] : g[2];
    hf2 c2i = hiL ? g[5] : g[3];
    #pragma unroll
    for (int k = 0; k < 8; ++k) {
        hf2 pr = lx2<XB>(hr[k]);
        hf2 pi = lx2<XB>(hi[k]);
        cfma2(c1r, c1i, c2r, c2i, hr[k], hi[k], pr, pi, hr[k], hi[k]);
    }
}

// CZ signs as sign-bit XOR. View A: e=(l<<10)|(n<<4)|w (verified r10/r15).
__device__ __forceinline__ void cz_A_h(hf2 hr[8], hf2 hi[8], int t) {
    const int n = t & 63, w = t >> 6;
    const int pT = (__popc(w & (w >> 1)) + __popc(n & (n >> 1)) + ((n & 1) & (w >> 3))) & 1;
    const int f0 = pT, f1 = pT ^ ((n >> 5) & 1);   // F1: cross term l0 & n5
    #pragma unroll
    for (int k = 0; k < 8; ++k) {
        const int stlo = __popc((2*k) & ((2*k) >> 1)) & 1;
        const int sthi = __popc((2*k+1) & ((2*k+1) >> 1)) & 1;
        const unsigned mask = ((f0 ^ stlo) ? 0x8000u : 0u)
                            | ((f1 ^ sthi) ? 0x80000000u : 0u);
        hr[k] = hxor(hr[k], mask); hi[k] = hxor(hi[k], mask);
    }
}
// View B: e9=n3,e8=n1,e7=n5,e6=n0,e5=n4,e4=n2 (verified r10/r15); cross = l3&n2.
__device__ __forceinline__ void cz_B_h(hf2 hr[8], hf2 hi[8], int t) {
    const int n = t & 63, w = t >> 6;
    const int n0 = n & 1, n1 = (n >> 1) & 1, n2 = (n >> 2) & 1;
    const int n3 = (n >> 3) & 1, n4 = (n >> 4) & 1, n5 = (n >> 5) & 1;
    const int pT = ((n2 & n4) ^ (n4 & n0) ^ (n0 & n5) ^ (n5 & n1) ^ (n1 & n3)
                    ^ (n3 & (w & 1)) ^ (__popc(w & (w >> 1)) & 1));
    const int f0 = pT, f1 = pT ^ n2;
    #pragma unroll
    for (int k = 0; k < 8; ++k) {
        const int fs = (k & 4) ? f1 : f0;           // l3 = k&4 selects F
        const int stlo = __popc((2*k) & ((2*k) >> 1)) & 1;
        const int sthi = __popc((2*k+1) & ((2*k+1) >> 1)) & 1;
        const unsigned mask = ((fs ^ stlo) ? 0x8000u : 0u)
                            | ((fs ^ sthi) ? 0x80000000u : 0u);
        hr[k] = hxor(hr[k], mask); hi[k] = hxor(hi[k], mask);
    }
}

// ---- prep: gates -> d_ws (batch-invariant; 1 block) ----
// hf2 table: 6 half-layers x 7 slots x 8 hf2; layer-0 fp32 gates after.
__global__ void qlg_prep(const float* __restrict__ wts, hf2* __restrict__ Gh,
                         f4* __restrict__ G0)
{
    const int t = threadIdx.x;
    if (t >= DEPTH * NQ) return;
    const int d = t / NQ, ww = t % NQ;
    const float p0 = wts[(d*NQ + ww)*3 + 0];
    const float p1 = wts[(d*NQ + ww)*3 + 1];
    const float p2 = wts[(d*NQ + ww)*3 + 2];
    float s0, c0, s1, c1, s2, c2;
    sincosf(0.5f*p0, &s0, &c0);
    sincosf(0.5f*p1, &s1, &c1);
    sincosf(0.5f*p2, &s2, &c2);
    // U = RY(p2) * RX(p1) * RZ(p0)
    f2 e0  = (f2){c0, -s0};
    f2 e0c = (f2){c0,  s0};
    f2 is1 = (f2){0.f, -s1};
    f2 m00 = c1 * e0;
    f2 m01 = cmul(is1, e0c);
    f2 m10 = cmul(is1, e0);
    f2 m11 = c1 * e0c;
    f2 u00 = c2*m00 - s2*m10;
    f2 u01 = c2*m01 - s2*m11;
    f2 u10 = s2*m00 + c2*m10;
    f2 u11 = s2*m01 + c2*m11;
    if (d == 0) {
        G0[ww*2 + 0] = (f4){u00.x, u00.y, u01.x, u01.y};
        G0[ww*2 + 1] = (f4){u10.x, u10.y, u11.x, u11.y};
        return;
    }
    // half-layers h0..h5 = (1,A),(1,B),(2,B),(2,A),(3,A),(3,B);
    // slots: A: q0,q1,q2,q3,q6,q8,q9   B: q10,q11,q12,q13,q4,q5,q7
    const bool isA = (ww <= 3) || (ww == 6) || (ww == 8) || (ww == 9);
    int slot;
    if (isA) slot = (ww <= 3) ? ww : (ww == 6 ? 4 : (ww == 8 ? 5 : 6));
    else     slot = (ww >= 10) ? (ww - 10) : (ww == 4 ? 4 : (ww == 5 ? 5 : 6));
    const int h = (d == 1) ? (isA ? 0 : 1)
                : (d == 2) ? (isA ? 3 : 2)
                           : (isA ? 4 : 5);
    hf2* g = Gh + (h*7 + slot)*8;
    if (slot == 3) {   // within-pair gate: column packing A=(u00,u11) B=(u01,u10)
        g[0] = h2of(u00.x, u11.x);
        g[1] = h2of(u00.y, u11.y);
        g[2] = h2of(u01.x, u10.x);
        g[3] = h2of(u01.y, u10.y);
        g[4] = g[5] = g[6] = g[7] = h2of(0.f, 0.f);
    } else {           // broadcast packing
        g[0] = h2of(u00.x, u00.x); g[1] = h2of(u00.y, u00.y);
        g[2] = h2of(u01.x, u01.x); g[3] = h2of(u01.y, u01.y);
        g[4] = h2of(u10.x, u10.x); g[5] = h2of(u10.y, u10.y);
        g[6] = h2of(u11.x, u11.x); g[7] = h2of(u11.y, u11.y);
    }
}

__global__ __launch_bounds__(1024)
void qlg_kernel(const float* __restrict__ cond,
                const float* __restrict__ Wenc,
                const float* __restrict__ benc,
                const hf2* __restrict__ Gh,
                const f4* __restrict__ G0,
                float* __restrict__ out)
{
    __shared__ hf2 st[DIM];                 // 64 KB remap buffer (f16 amps)
    __shared__ f2 qv[NQ][2];
    __shared__ f2 Phi[128];
    __shared__ f2 Plo[128];
    __shared__ float wred[16][NQ];
    __shared__ float lat[NQ];

    const int b = blockIdx.x;
    const int t = threadIdx.x;
    const int n = t & 63, w = t >> 6;
    const int bB = (w << 10)
                 | (((n >> 3) & 1) << 5) | (((n >> 1) & 1) << 4)
                 | (((n >> 5) & 1) << 3) | ((n & 1) << 2)
                 | (((n >> 4) & 1) << 1) | ((n >> 2) & 1);

    // ---- stage 1+2 merged: embedding (SiLU) + per-wire 2-vectors ----
    if (t < NQ) {
        float s = benc[t];
        #pragma unroll
        for (int k = 0; k < NQ; ++k) s += cond[b*NQ + k] * Wenc[t*NQ + k];
        float v = s / (1.0f + __expf(-s));
        float sn, cs;
        sincosf(0.5f*v, &sn, &cs);
        f2 a0 = (f2){cs*cs,  sn*sn};
        f2 a1 = (f2){sn*cs, -sn*cs};
        f4 va = G0[t*2], vb = G0[t*2 + 1];
        f2 u00 = (f2){va.x, va.y}, u01 = (f2){va.z, va.w};
        f2 u10 = (f2){vb.x, vb.y}, u11 = (f2){vb.z, vb.w};
        qv[t][0] = cmul(u00, a0) + cmul(u01, a1);
        qv[t][1] = cmul(u10, a0) + cmul(u11, a1);
    }
    __syncthreads();

    // ---- stage 3: partial-product tables (fp32) ----
    if (t < 128) {
        f2 p = qv[0][(t >> 6) & 1];
        #pragma unroll
        for (int ww = 1; ww <= 6; ++ww) p = cmul(p, qv[ww][(t >> (6 - ww)) & 1]);
        Phi[t] = p;
    } else if (t < 256) {
        const int j = t - 128;
        f2 p = qv[7][(j >> 6) & 1];
        #pragma unroll
        for (int ww = 8; ww <= 13; ++ww) p = cmul(p, qv[ww][(j >> (13 - ww)) & 1]);
        Plo[j] = p;
    }
    __syncthreads();

    // ---- stage 4: build product state in f16 planes (view A), CZ0 fused ----
    hf2 hr[8], hi[8];
    {
        f2 plo = Plo[((n & 7) << 4) | w];
        #pragma unroll
        for (int k = 0; k < 8; ++k) {
            const int l0 = 2*k, l1 = 2*k + 1;
            const int e0 = (l0 << 10) | (n << 4) | w;
            const int e1 = (l1 << 10) | (n << 4) | w;
            f2 a0 = cmul(Phi[(l0 << 3) | (n >> 3)], plo) * czsgn(e0);
            f2 a1 = cmul(Phi[(l1 << 3) | (n >> 3)], plo) * czsgn(e1);
            hr[k] = h2of(a0.x, a1.x);
            hi[k] = h2of(a0.y, a1.y);
        }
    }

    // ---- stage 5: 6 half-layers ----
    #pragma unroll
    for (int h = 0; h < 6; ++h) {
        const hf2* __restrict__ g = Gh + h*7*8;
        reg_gate_h<4>(hr, hi, g + 0*8);     // l-mask 8
        reg_gate_h<2>(hr, hi, g + 1*8);     // l-mask 4
        reg_gate_h<1>(hr, hi, g + 2*8);     // l-mask 2
        pair_gate_h(hr, hi, g + 3*8);       // l-mask 1
        lane_gate_h<8>(hr, hi, g + 4*8, t);
        lane_gate_h<2>(hr, hi, g + 5*8, t);
        lane_gate_h<1>(hr, hi, g + 6*8, t);
        if (h == 1)      cz_B_h(hr, hi, t); // CZ after layer 1 (view B)
        else if (h == 3) cz_A_h(hr, hi, t); // CZ after layer 2 (view A)
        if (h == 0 || h == 4) {             // remap A -> B
            #pragma unroll
            for (int k = 0; k < 8; ++k) {
                st[t + ((2*k)   << 10)] = (hf2){hr[k].x, hi[k].x};
                st[t + ((2*k+1) << 10)] = (hf2){hr[k].y, hi[k].y};
            }
            __syncthreads();
            #pragma unroll
            for (int k = 0; k < 8; ++k) {
                hf2 w0 = st[bB + ((2*k)   << 6)];
                hf2 w1 = st[bB + ((2*k+1) << 6)];
                hr[k] = (hf2){w0.x, w1.x};
                hi[k] = (hf2){w0.y, w1.y};
            }
        } else if (h == 2) {                // remap B -> A
            #pragma unroll
            for (int k = 0; k < 8; ++k) {
                st[bB + ((2*k)   << 6)] = (hf2){hr[k].x, hi[k].x};
                st[bB + ((2*k+1) << 6)] = (hf2){hr[k].y, hi[k].y};
            }
            __syncthreads();
            #pragma unroll
            for (int k = 0; k < 8; ++k) {
                hf2 w0 = st[t + ((2*k)   << 10)];
                hf2 w1 = st[t + ((2*k+1) << 10)];
                hr[k] = (hf2){w0.x, w1.x};
                hi[k] = (hf2){w0.y, w1.y};
            }
        }
    }
    // (CZ after layer 3 dropped: |psi|^2 invariant)

    // ---- fused probability reduction (view B, fp32 accumulate) ----
    float SU, Q10, Q11, Q12, Q13;
    {
        SU = Q10 = Q11 = Q12 = Q13 = 0.f;
        #pragma unroll
        for (int k = 0; k < 8; ++k) {
            float rl = (float)hr[k].x, rh = (float)hr[k].y;
            float il = (float)hi[k].x, ih = (float)hi[k].y;
            float pl = rl*rl + il*il;
            float ph = rh*rh + ih*ih;
            float g2 = pl + ph;
            SU  += g2;
            Q13 += pl - ph;                 // l0
            Q10 += (k & 4) ? -g2 : g2;      // l3
            Q11 += (k & 2) ? -g2 : g2;      // l2
            Q12 += (k & 1) ? -g2 : g2;      // l1
        }
    }

    // ---- stage 6: reduce to 14 expectations, layernorm (fp32) ----
    // View-B thread-uniform sign bits: q0:t9 q1:t8 q2:t7 q3:t6 q4:t3 q5:t1
    // q6:t5 q7:t0 q8:t4 q9:t2.
    {
        const int lane = t & 63, wv = t >> 6;
        const int sbit[10] = {9, 8, 7, 6, 3, 1, 5, 0, 4, 2};
        #pragma unroll
        for (int ww = 0; ww < NQ; ++ww) {
            float v;
            if      (ww == 10) v = Q10;
            else if (ww == 11) v = Q11;
            else if (ww == 12) v = Q12;
            else if (ww == 13) v = Q13;
            else               v = ((t >> sbit[ww]) & 1) ? -SU : SU;
            #pragma unroll
            for (int off = 32; off > 0; off >>= 1) v += __shfl_down(v, off, 64);
            if (lane == 0) wred[wv][ww] = v;
        }
    }
    __syncthreads();
    if (t < NQ) {
        float s = 0.f;
        #pragma unroll
        for (int k = 0; k < 16; ++k) s += wred[k][t];
        lat[t] = s;
    }
    __syncthreads();
    if (t < NQ) {
        float mu = 0.f;
        #pragma unroll
        for (int k = 0; k < NQ; ++k) mu += lat[k];
        mu *= (1.0f / NQ);
        float var = 0.f;
        #pragma unroll
        for (int k = 0; k < NQ; ++k) { float dv = lat[k] - mu; var += dv*dv; }
        var *= (1.0f / NQ);
        out[b*NQ + t] = (lat[t] - mu) * rsqrtf(var + 1e-5f);
    }
}

extern "C" void kernel_launch(void* const* d_in, const int* in_sizes, int n_in,
                              void* d_out, int out_size, void* d_ws, size_t ws_size,
                              hipStream_t stream)
{
    (void)n_in; (void)ws_size; (void)out_size;
    const float* cond = (const float*)d_in[0];
    const float* Wenc = (const float*)d_in[1];
    const float* benc = (const float*)d_in[2];
    const float* wts  = (const float*)d_in[3];
    float* out = (float*)d_out;
    hf2* Gh = (hf2*)d_ws;                        // 336 hf2 = 1344 B
    f4* G0 = (f4*)((char*)d_ws + 2048);          // 28 f4 = 448 B
    const int B = in_sizes[0] / NQ;              // 256
    qlg_prep<<<dim3(1), dim3(64), 0, stream>>>(wts, Gh, G0);
    qlg_kernel<<<dim3(B), dim3(1024), 0, stream>>>(cond, Wenc, benc, Gh, G0, out);
}